// Round 12
// baseline (1081.949 us; speedup 1.0000x reference)
//
#include <hip/hip_runtime.h>
#include <hip/hip_bf16.h>
#include <cstddef>

// FAN_39273180955145 — round 22. r21 (819us) showed wall time tracks
// critical-path cuts ~1:1, yet ~70% of cycles nothing issues. The one region
// untouched since r10: the LN epilogue — 16 unrolled reg-iterations each
// with a SERIAL 5-round shfl_xor butterfly (10 dependent ds_bpermute @
// ~120cyc = ~1.2k cyc latency per reg-iteration; up to ~19k cyc/layer if
// the scheduler doesn't interleave across iterations). r22 batches it:
//  pass 1: residual+scale, partials -> s1v[16]/s2v[16] (static idx = regs);
//  pass 2: 5 butterfly rounds x 32 INDEPENDENT shuffles (all regs both sums)
//          -> latency pipelined, ~1.2k cyc total;
//  pass 3: stats + normalize + writeback.
// Per-reg reduce sequence is bit-identical (only cross-reg interleave
// changes) -> absmax unchanged. Everything else byte-identical to r21
// (kh-free qh-in-regs structure, cvt_pk packing, softmax folding,
// 3 barriers/layer, launch_bounds(512,2)).

typedef unsigned short u16;
typedef unsigned int u32;
typedef short short8 __attribute__((ext_vector_type(8)));
typedef u32 u32x2 __attribute__((ext_vector_type(2)));
typedef float floatx16 __attribute__((ext_vector_type(16)));
typedef float f32x4 __attribute__((ext_vector_type(4)));

__device__ __forceinline__ float b2f(u16 u){ return __uint_as_float(((u32)u) << 16); }
__device__ __forceinline__ u16 f2b(float f){
  __hip_bfloat16 h = __float2bfloat16(f);          // RNE, = old manual round
  return *reinterpret_cast<u16*>(&h);
}
__device__ __forceinline__ u32 pk2(float a, float b){
  float2 t; t.x = a; t.y = b;
  __hip_bfloat162 h = __float22bfloat162_rn(t);    // v_cvt_pk_bf16_f32 (lo=a)
  return *reinterpret_cast<u32*>(&h);
}
// flagged input load: f32 ? fp32 : bf16; non-finite -> 0
__device__ __forceinline__ float ldf(const u16* p, size_t i, int f32){
  float v = f32 ? ((const float*)p)[i] : b2f(p[i]);
  return __builtin_isfinite(v) ? v : 0.f;
}
// [rows][128 bf16] region, 256B rows, 16B-chunk xor swizzle
__device__ __forceinline__ int swz(int row, int ch){ return (row << 8) | ((ch ^ (row & 15)) << 4); }
// [rows][256 bf16] region, 512B rows, 32 chunks; xor low4 only (bijective)
__device__ __forceinline__ int swz2(int row, int ch){ return (row << 9) | ((ch ^ (row & 15)) << 4); }
__device__ __forceinline__ floatx16 fz(){
  floatx16 z;
#pragma unroll
  for (int i = 0; i < 16; ++i) z[i] = 0.f;
  return z;
}
__device__ __forceinline__ floatx16 MF(short8 a, short8 b, floatx16 c){
  return __builtin_amdgcn_mfma_f32_32x32x16_bf16(a, b, c, 0, 0, 0);
}
// C-layout 32x32 tile (by value) -> k-chunk fragment via xor-32 exchange
// (r4-verified). cvt_pk packing + verified __shfl_xor lane exchange.
__device__ __forceinline__ short8 frag_from(floatx16 cv, int half, int q5){
  int r0 = half * 8;
  u32 e01 = pk2(cv[r0 + 0], cv[r0 + 1]);
  u32 e23 = pk2(cv[r0 + 2], cv[r0 + 3]);
  u32 o01 = pk2(cv[r0 + 4], cv[r0 + 5]);
  u32 o23 = pk2(cv[r0 + 6], cv[r0 + 7]);
  u32 s0 = q5 ? e01 : o01;
  u32 s1 = q5 ? e23 : o23;
  u32 r0v = __shfl_xor(s0, 32);
  u32 r1v = __shfl_xor(s1, 32);
  union { u32 u[4]; short8 v; } un;
  un.u[0] = q5 ? r0v : e01;
  un.u[1] = q5 ? r1v : e23;
  un.u[2] = q5 ? o01 : r0v;
  un.u[3] = q5 ? o23 : r1v;
  return un.v;
}

// ---------------- dtype detector (r4-verified) ----------------
__global__ __launch_bounds__(256) void k_detect(const u16* x, int* dflag){
  __shared__ int red[256];
  int t = threadIdx.x, cnt = 0;
  for (int i = t; i < 4096; i += 256){
    u16 v = x[2 * i];
    int e = (v >> 7) & 0xFF;
    if (e == 0xFF || e >= 0x90 || (e > 0 && e <= 0x20)) ++cnt;
  }
  red[t] = cnt;
  __syncthreads();
  for (int off = 128; off > 0; off >>= 1){
    if (t < off) red[t] += red[t + off];
    __syncthreads();
  }
  if (t == 0) dflag[0] = (red[0] > 1000) ? 1 : 0;
}

// ---------------- prep kernels ----------------

// MrowT[a][b] = M'[b,a]; vWT[d][e] = vW[e][d]; uv = u'.
__global__ __launch_bounds__(128) void k_prepw(const u16* qW, const u16* kW, const u16* vW,
                                               const u16* qb, u16* MrT, u16* vWT, float* uv,
                                               const int* dflag){
  int fl = dflag[0];
  int i = blockIdx.x >> 7, f = blockIdx.x & 127, e = threadIdx.x;
  size_t qo = (size_t)(i * 128 + e) * 128;   // qW row e
  size_t ko = (size_t)(i * 128 + f) * 128;   // kW row f
  float m = 0.f;
  for (int d = 0; d < 128; ++d) m += ldf(qW, qo + d, fl) * ldf(kW, ko + d, fl);
  const float RS = 0.08838834764831845f;  // 1/sqrt(128)
  MrT[(i * 128 + f) * 128 + e] = f2b(m * RS);                 // MrowT[f][e] = M'[e,f]
  vWT[(i * 128 + f) * 128 + e] = f2b(ldf(vW, qo + f, fl));    // vWT[d][e] = vW[e][d]
  __shared__ float red[128];
  red[e] = ldf(kW, ko + e, fl) * ldf(qb, (size_t)i * 128 + e, fl);
  __syncthreads();
  for (int off = 64; off > 0; off >>= 1){
    if (e < off) red[e] += red[e + off];
    __syncthreads();
  }
  if (e == 0) uv[i * 128 + f] = red[0] * RS;
}

__global__ __launch_bounds__(256) void k_h1t(const u16* h1W, u16* h1WT, const int* dflag){
  int fl = dflag[0];
  __shared__ u16 tile[64][130];
  int k0 = blockIdx.x * 64, tid = threadIdx.x;
#pragma unroll 4
  for (int it = 0; it < 32; ++it){
    int r = it * 2 + (tid >> 7), c = tid & 127;
    tile[r][c] = f2b(ldf(h1W, (size_t)(k0 + r) * 128 + c, fl));
  }
  __syncthreads();
#pragma unroll 4
  for (int it = 0; it < 32; ++it){
    int idx = it * 256 + tid, n = idx >> 6, kk = idx & 63;
    h1WT[(size_t)n * 32896 + k0 + kk] = tile[kk][n];
  }
}

// -------- fused embed + 2 attention layers; h in LDS; one block = one batch --------

__global__ __launch_bounds__(512, 2) void k_fan(
    const u16* x, const u16* sW, const u16* sb, const u16* hW, const u16* hbe,
    const u16* MrT, const float* uv, const u16* vWT, const u16* vb,
    const u16* lng, const u16* lnb,
    u16* hgq, u16* se, int qoff, const int* dflag){
  __shared__ alignas(16) u16 hL[32768];    // h   [256 s][128 f], swz,  64KB
  __shared__ alignas(16) u16 vt[32768];    // vT  [128 d][256 t], swz2, 64KB
  __shared__ alignas(16) float c_all[256]; // c_t + LKOFF - 8, whole layer
  __shared__ float u_lds[128];             // u' for current layer
  int fl = dflag[0];
  int bl = blockIdx.x;
  int b = qoff + bl;
  int tid = threadIdx.x, w = tid >> 6, lane = tid & 63, l31 = lane & 31, q5 = lane >> 5;
  size_t xo = (size_t)b * 272;
  const float LKOFF = -20.72326584f;       // ln(1e-9); off-diag log-kernel value

  // scalar embedding (lanes 0..127)
  if (tid < 128){
    float acc = ldf(sb, tid, fl);
#pragma unroll
    for (int j = 0; j < 16; ++j) acc += ldf(x, xo + j, fl) * ldf(sW, (size_t)j * 128 + tid, fl);
    se[(size_t)b * 128 + tid] = f2b(acc);
  }
  // history embedding -> hL (pair-packed cvt_pk)
#pragma unroll
  for (int it = 0; it < 8; ++it){
    int c = it * 512 + tid, s = c >> 4, ch = c & 15;
    float xv = ldf(x, xo + 16 + s, fl);
    float f[8];
#pragma unroll
    for (int j = 0; j < 8; ++j)
      f[j] = xv * ldf(hW, ch * 8 + j, fl) + ldf(hbe, ch * 8 + j, fl);
    union { u32 u[4]; short8 v; } rr_;
#pragma unroll
    for (int j2 = 0; j2 < 4; ++j2) rr_.u[j2] = pk2(f[2 * j2], f[2 * j2 + 1]);
    *(short8*)((char*)hL + swz(s, ch)) = rr_.v;
  }

  int mtv = w & 3;                         // d-chunk for v producer
  int scol = 32 * w + l31;

#pragma unroll 1
  for (int li = 0; li < 2; ++li){
    const u16* Ta   = MrT + li * 16384;
    const u16* vWTi = vWT + li * 16384;
    if (tid < 128) u_lds[tid] = uv[li * 128 + tid];
    float vbl = ldf(vb, (size_t)li * 128 + 32 * mtv + l31, fl);
    __syncthreads();                 // hL (embed/prev epilogue) + u_lds visible

    // ---- qh_s = h_s.M' into registers: D[e][s] tiles, lane = col = s = scol.
    short8 qhf[8];
#pragma unroll
    for (int et = 0; et < 4; ++et){
      floatx16 qa = fz();
#pragma unroll 2
      for (int kc = 0; kc < 8; ++kc){
        short8 av = *(const short8*)(Ta + (32 * et + l31) * 128 + kc * 16 + q5 * 8);
        short8 bq = *(const short8*)((char*)hL + swz(32 * w + l31, 2 * kc + q5));
        qa = MF(av, bq, qa);
      }
      qhf[2 * et + 0] = frag_from(qa, 0, q5);   // e = 32et + 0..15
      qhf[2 * et + 1] = frag_from(qa, 1, q5);   // e = 32et + 16..31
    }

    // ---- c_all[t] = u'.h_t + (LKOFF - 8)  [softmax baseline folded in]
    {
      int row = 32 * w + l31;
      float dot = 0.f;
#pragma unroll 2
      for (int kc = 0; kc < 8; ++kc){
        int ch = 2 * kc + q5;
        short8 hv = *(const short8*)((char*)hL + swz(row, ch));
#pragma unroll
        for (int j = 0; j < 8; ++j) dot += u_lds[ch * 8 + j] * b2f(hv[j]);
      }
      dot += __shfl_xor(dot, 32);
      if (q5 == 0) c_all[row] = dot + (LKOFF - 8.f);
    }

    // ---- v producer: whole layer. vt[d][t] = sum_e h[t,e] vW[e,d] + vb[d].
    {
      const u16* Va = vWTi + (32 * mtv + l31) * 128 + q5 * 8;
#pragma unroll 1
      for (int u = 0; u < 4; ++u){
        int tc = (w >> 2) * 4 + u;
        floatx16 va = fz();
#pragma unroll 2
        for (int kc = 0; kc < 8; ++kc){
          short8 avV = *(const short8*)(Va + kc * 16);
          short8 bh  = *(const short8*)((char*)hL + swz(32 * tc + l31, 2 * kc + q5));
          va = MF(bh, avV, va);
        }
        // D[t][d]: lane = d-col, regs = t; 4 consecutive t -> one 8B chunk
#pragma unroll
        for (int qd = 0; qd < 4; ++qd){
          u32x2 pv;
          pv.x = pk2(va[4 * qd + 0] + vbl, va[4 * qd + 1] + vbl);
          pv.y = pk2(va[4 * qd + 2] + vbl, va[4 * qd + 3] + vbl);
          *(u32x2*)((char*)vt + swz2(32 * mtv + l31, 4 * tc + qd) + 8 * q5) = pv;
        }
      }
    }
    __syncthreads();               // vt + c_all complete

    float ls_a = 0.f, ls_b = 0.f;
    floatx16 oacc[4];
#pragma unroll
    for (int nt = 0; nt < 4; ++nt) oacc[nt] = fz();

    // ---- consumer: scores + exp + P@V over 8 t-subtiles; NO internal barriers
#pragma unroll 1
    for (int mt = 0; mt < 8; ++mt){
      floatx16 sa = fz();
      __builtin_amdgcn_s_setprio(1);
#pragma unroll
      for (int kc = 0; kc < 8; ++kc){
        short8 ah = *(const short8*)((char*)hL + swz(32 * mt + l31, 2 * kc + q5));
        sa = MF(ah, qhf[kc], sa);
      }
      __builtin_amdgcn_s_setprio(0);
      // softmax: v = sa + c2[tg]; diag removes the folded off-diag LKOFF.
#pragma unroll
      for (int g = 0; g < 4; ++g){
        f32x4 c4 = *(const f32x4*)&c_all[32 * mt + 8 * g + 4 * q5];
#pragma unroll
        for (int k = 0; k < 4; ++k){
          int reg = 4 * g + k;
          int tg = 32 * mt + 8 * g + 4 * q5 + k;
          float v = sa[reg] + c4[k];
          if (tg == scol) v -= LKOFF;
          v = fminf(fmaxf(v, -58.f), 42.f);
          float p = __expf(v);       // fixed-max softmax, shift folded into c2
          sa[reg] = p;
          if (reg & 1) ls_b += p; else ls_a += p;
        }
      }
      // pf frags computed BEFORE the bv loads so sa dies here (register diet)
      short8 pf0 = frag_from(sa, 0, q5);
      short8 pf1 = frag_from(sa, 1, q5);
      __builtin_amdgcn_s_setprio(1);
#pragma unroll
      for (int nt = 0; nt < 4; ++nt){
        short8 bv0 = *(const short8*)((char*)vt + swz2(32 * nt + l31, 4 * mt + 0 + q5));
        oacc[nt] = MF(pf0, bv0, oacc[nt]);
        short8 bv1 = *(const short8*)((char*)vt + swz2(32 * nt + l31, 4 * mt + 2 + q5));
        oacc[nt] = MF(pf1, bv1, oacc[nt]);
      }
      __builtin_amdgcn_s_setprio(0);
    }
    __syncthreads();                   // all hL reads done before epilogue writes

    // ---- epilogue: /l, +residual, LayerNorm, write back to hL (own rows only)
    // r22: batched butterfly — per-reg partials first, then 5 rounds of 32
    // independent shuffles (latency pipelined), then stats+normalize+write.
    float ls_tot = ls_a + ls_b;
    float l_run = ls_tot + __shfl_xor(ls_tot, 32);
    float linv = 1.f / l_run;
    float gv[4], bbv[4];
#pragma unroll
    for (int nt = 0; nt < 4; ++nt){
      gv[nt]  = ldf(lng, (size_t)li * 128 + 32 * nt + l31, fl);
      bbv[nt] = ldf(lnb, (size_t)li * 128 + 32 * nt + l31, fl);
    }
    float s1v[16], s2v[16];
    // pass 1: v = oacc*lrv + res; partial sums per reg
#pragma unroll
    for (int reg = 0; reg < 16; ++reg){
      int rr = (reg & 3) + 8 * (reg >> 2) + 4 * q5;
      int srow = 32 * w + rr;
      float lrv = __shfl(linv, rr);
      float s1 = 0.f, s2 = 0.f;
#pragma unroll
      for (int nt = 0; nt < 4; ++nt){
        int d = 32 * nt + l31;
        float res = b2f(*(const u16*)((char*)hL + swz(srow, d >> 3) + (d & 7) * 2));
        float v = oacc[nt][reg] * lrv + res;
        oacc[nt][reg] = v;
        s1 += v; s2 += v * v;
      }
      s1v[reg] = s1; s2v[reg] = s2;
    }
    // pass 2: batched butterfly (bit-identical per-reg sequence)
#pragma unroll
    for (int off = 1; off < 32; off <<= 1){
#pragma unroll
      for (int reg = 0; reg < 16; ++reg){
        s1v[reg] += __shfl_xor(s1v[reg], off);
        s2v[reg] += __shfl_xor(s2v[reg], off);
      }
    }
    // pass 3: stats + normalize + write
#pragma unroll
    for (int reg = 0; reg < 16; ++reg){
      int rr = (reg & 3) + 8 * (reg >> 2) + 4 * q5;
      int srow = 32 * w + rr;
      float mu = s1v[reg] * 0.0078125f;
      float rs = rsqrtf(fmaxf(s2v[reg] * 0.0078125f - mu * mu, 0.f) + 1e-5f);
#pragma unroll
      for (int nt = 0; nt < 4; ++nt){
        int d = 32 * nt + l31;
        float v = (oacc[nt][reg] - mu) * rs * gv[nt] + bbv[nt];
        *(u16*)((char*)hL + swz(srow, d >> 3) + (d & 7) * 2) = f2b(v);
      }
    }
    __syncthreads();                   // hL update visible before next layer / store
  }

  // final h -> global, coalesced 16B chunks
#pragma unroll
  for (int it = 0; it < 8; ++it){
    int c = it * 512 + tid, row = c >> 4, ch = c & 15;
    *(short8*)(hgq + (size_t)bl * 32768 + row * 128 + ch * 8) =
        *(const short8*)((char*)hL + swz(row, ch));
  }
}

// ---------------- MLP head ----------------

__global__ __launch_bounds__(256) void k_mlp1(const u16* se, const u16* hgq, const u16* h1WT,
                                              float* part, int qoff, int nb){
  int mb = blockIdx.x, ks = blockIdx.y;
  int tid = threadIdx.x, w = tid >> 6, lane = tid & 63, l31 = lane & 31, q5 = lane >> 5;
  int b0 = mb * 32;
  floatx16 acc = fz();
  const u16* brow = h1WT + (size_t)(32 * w + l31) * 32896;
  int br = b0 + l31;
  const u16* seb = se + (size_t)(qoff + br) * 128;
  const u16* hb = hgq + (size_t)br * 32768;
  for (int kk = 0; kk < 257; ++kk){
    int kbase = ks * 4112 + kk * 16;
    const u16* ap = (kbase < 128) ? (seb + kbase + q5 * 8) : (hb + (kbase - 128) + q5 * 8);
    short8 a = *(const short8*)ap;
    short8 bf = *(const short8*)(brow + kbase + q5 * 8);
    acc = MF(a, bf, acc);
  }
#pragma unroll
  for (int reg = 0; reg < 16; ++reg){
    int rr = (reg & 3) + 8 * (reg >> 2) + 4 * q5;
    part[(size_t)ks * nb * 128 + (size_t)(b0 + rr) * 128 + 32 * w + l31] = acc[reg];
  }
}

__global__ __launch_bounds__(256) void k_mlp1red(const float* part, const u16* h1b, float* z1q,
                                                 const int* dflag, int nb){
  int fl = dflag[0];
  int idx = blockIdx.x * 256 + threadIdx.x;    // 0..nb*128-1
  float s = ldf(h1b, idx & 127, fl);
  size_t stride = (size_t)nb * 128;
#pragma unroll
  for (int ks = 0; ks < 8; ++ks) s += part[(size_t)ks * stride + idx];
  z1q[idx] = fmaxf(s, 0.f);
}

__global__ __launch_bounds__(256) void k_mlp2(const float* z1, const u16* h2W, const u16* h2b,
                                              float* z2, const int* dflag){
  int fl = dflag[0];
  int idx = blockIdx.x * 256 + threadIdx.x;    // 0..131071
  int b = idx >> 6, j = idx & 63;
  float s = ldf(h2b, j, fl);
  const float* zr = z1 + (size_t)b * 128;
  for (int k = 0; k < 128; ++k) s += zr[k] * ldf(h2W, (size_t)k * 64 + j, fl);
  z2[idx] = fmaxf(s, 0.f);
}

__global__ __launch_bounds__(256) void k_mlp3(const float* z2, const u16* h3W, const u16* h3b,
                                              void* out, const int* dflag){
  int fl = dflag[0];
  int b = blockIdx.x * 256 + threadIdx.x;      // 0..2047
  float s = ldf(h3b, 0, fl);
  const float* zr = z2 + (size_t)b * 64;
#pragma unroll
  for (int j = 0; j < 64; ++j) s += zr[j] * ldf(h3W, j, fl);
  if (!__builtin_isfinite(s)) s = 0.f;
  if (fl) ((float*)out)[b] = s;
  else    ((u16*)out)[b] = f2b(s);
}

// ---------------- launch ----------------

extern "C" void kernel_launch(void* const* d_in, const int* in_sizes, int n_in,
                              void* d_out, int out_size, void* d_ws, size_t ws_size,
                              hipStream_t stream) {
  const u16* x   = (const u16*)d_in[0];
  const u16* sW  = (const u16*)d_in[1];
  const u16* sb  = (const u16*)d_in[2];
  const u16* hW  = (const u16*)d_in[3];
  const u16* hb  = (const u16*)d_in[4];
  const u16* qW  = (const u16*)d_in[5];
  const u16* qb  = (const u16*)d_in[6];
  const u16* kW  = (const u16*)d_in[7];
  // d_in[8] = kb : cancels in softmax, unused
  const u16* vW  = (const u16*)d_in[9];
  const u16* vb  = (const u16*)d_in[10];
  const u16* lng = (const u16*)d_in[11];
  const u16* lnb = (const u16*)d_in[12];
  const u16* h1W = (const u16*)d_in[13];
  const u16* h1b = (const u16*)d_in[14];
  const u16* h2W = (const u16*)d_in[15];
  const u16* h2b = (const u16*)d_in[16];
  const u16* h3W = (const u16*)d_in[17];
  const u16* h3b = (const u16*)d_in[18];

  // full-pass mode (r5-r8 ran this branch); quarter mode fallback.
  const int nb = (ws_size >= 153600000ull) ? 2048 : 512;
  const int nq = 2048 / nb;

  char* W = (char*)d_ws;
  size_t o = 0;
  u16*   hg    = (u16*)(W + o); o += (size_t)nb * 65536;   // nb*32768*2
  u16*   h1WT  = (u16*)(W + o); o += 8421376;
  u16*   se    = (u16*)(W + o); o += 524288;               // always full 2048x128 bf16
  u16*   MrT   = (u16*)(W + o); o += 65536;
  u16*   vWT   = (u16*)(W + o); o += 65536;
  float* uv    = (float*)(W + o); o += 1024;
  float* part  = (float*)(W + o); o += (size_t)nb * 4096;  // 8 * nb*128 * 4B
  float* z1    = (float*)(W + o); o += 1048576;            // always full
  float* z2    = (float*)(W + o); o += 524288;
  int*   dflag = (int*)(W + o);

  k_detect<<<1, 256, 0, stream>>>(x, dflag);
  k_prepw<<<256, 128, 0, stream>>>(qW, kW, vW, qb, MrT, vWT, uv, dflag);
  k_h1t<<<514, 256, 0, stream>>>(h1W, h1WT, dflag);

  for (int q = 0; q < nq; ++q){
    int qoff = q * nb;
    k_fan<<<nb, 512, 0, stream>>>(x, sW, sb, hW, hb, MrT, uv, vWT, vb,
                                  lng, lnb, hg, se, qoff, dflag);
    k_mlp1<<<dim3(nb / 32, 8), 256, 0, stream>>>(se, hg, h1WT, part, qoff, nb);
    k_mlp1red<<<nb / 2, 256, 0, stream>>>(part, h1b, z1 + (size_t)qoff * 128, dflag, nb);
  }

  k_mlp2<<<512, 256, 0, stream>>>(z1, h2W, h2b, z2, dflag);
  k_mlp3<<<8, 256, 0, stream>>>(z2, h3W, h3b, d_out, dflag);
}

// Round 13
// 996.655 us; speedup vs baseline: 1.0856x; 1.0856x over previous
//
#include <hip/hip_runtime.h>
#include <hip/hip_bf16.h>
#include <cstddef>

// FAN_39273180955145 — round 23. r22 (batch-16 butterfly) regressed 819->868:
// s1v[16]+s2v[16] = 32 extra live regs across the butterfly re-spilled
// (WRITE 171->351MB) — hypothesis confounded, not tested. r23 = same idea,
// register-bounded: GROUP-OF-4 batching. Per group: 4 partial pairs (8 live
// regs), 5 butterfly rounds x 8 independent shuffles (4x latency overlap vs
// r21 serial), normalize+write, release. Peak extra live = 8 floats (under
// r21 headroom). Bit-identical per-reg reduce sequence. Everything else
// byte-identical to r21 (819us best: kh-free qh-in-regs, cvt_pk packing,
// softmax folding, 3 barriers/layer, launch_bounds(512,2)).

typedef unsigned short u16;
typedef unsigned int u32;
typedef short short8 __attribute__((ext_vector_type(8)));
typedef u32 u32x2 __attribute__((ext_vector_type(2)));
typedef float floatx16 __attribute__((ext_vector_type(16)));
typedef float f32x4 __attribute__((ext_vector_type(4)));

__device__ __forceinline__ float b2f(u16 u){ return __uint_as_float(((u32)u) << 16); }
__device__ __forceinline__ u16 f2b(float f){
  __hip_bfloat16 h = __float2bfloat16(f);          // RNE, = old manual round
  return *reinterpret_cast<u16*>(&h);
}
__device__ __forceinline__ u32 pk2(float a, float b){
  float2 t; t.x = a; t.y = b;
  __hip_bfloat162 h = __float22bfloat162_rn(t);    // v_cvt_pk_bf16_f32 (lo=a)
  return *reinterpret_cast<u32*>(&h);
}
// flagged input load: f32 ? fp32 : bf16; non-finite -> 0
__device__ __forceinline__ float ldf(const u16* p, size_t i, int f32){
  float v = f32 ? ((const float*)p)[i] : b2f(p[i]);
  return __builtin_isfinite(v) ? v : 0.f;
}
// [rows][128 bf16] region, 256B rows, 16B-chunk xor swizzle
__device__ __forceinline__ int swz(int row, int ch){ return (row << 8) | ((ch ^ (row & 15)) << 4); }
// [rows][256 bf16] region, 512B rows, 32 chunks; xor low4 only (bijective)
__device__ __forceinline__ int swz2(int row, int ch){ return (row << 9) | ((ch ^ (row & 15)) << 4); }
__device__ __forceinline__ floatx16 fz(){
  floatx16 z;
#pragma unroll
  for (int i = 0; i < 16; ++i) z[i] = 0.f;
  return z;
}
__device__ __forceinline__ floatx16 MF(short8 a, short8 b, floatx16 c){
  return __builtin_amdgcn_mfma_f32_32x32x16_bf16(a, b, c, 0, 0, 0);
}
// C-layout 32x32 tile (by value) -> k-chunk fragment via xor-32 exchange
// (r4-verified). cvt_pk packing + verified __shfl_xor lane exchange.
__device__ __forceinline__ short8 frag_from(floatx16 cv, int half, int q5){
  int r0 = half * 8;
  u32 e01 = pk2(cv[r0 + 0], cv[r0 + 1]);
  u32 e23 = pk2(cv[r0 + 2], cv[r0 + 3]);
  u32 o01 = pk2(cv[r0 + 4], cv[r0 + 5]);
  u32 o23 = pk2(cv[r0 + 6], cv[r0 + 7]);
  u32 s0 = q5 ? e01 : o01;
  u32 s1 = q5 ? e23 : o23;
  u32 r0v = __shfl_xor(s0, 32);
  u32 r1v = __shfl_xor(s1, 32);
  union { u32 u[4]; short8 v; } un;
  un.u[0] = q5 ? r0v : e01;
  un.u[1] = q5 ? r1v : e23;
  un.u[2] = q5 ? o01 : r0v;
  un.u[3] = q5 ? o23 : r1v;
  return un.v;
}

// ---------------- dtype detector (r4-verified) ----------------
__global__ __launch_bounds__(256) void k_detect(const u16* x, int* dflag){
  __shared__ int red[256];
  int t = threadIdx.x, cnt = 0;
  for (int i = t; i < 4096; i += 256){
    u16 v = x[2 * i];
    int e = (v >> 7) & 0xFF;
    if (e == 0xFF || e >= 0x90 || (e > 0 && e <= 0x20)) ++cnt;
  }
  red[t] = cnt;
  __syncthreads();
  for (int off = 128; off > 0; off >>= 1){
    if (t < off) red[t] += red[t + off];
    __syncthreads();
  }
  if (t == 0) dflag[0] = (red[0] > 1000) ? 1 : 0;
}

// ---------------- prep kernels ----------------

// MrowT[a][b] = M'[b,a]; vWT[d][e] = vW[e][d]; uv = u'.
__global__ __launch_bounds__(128) void k_prepw(const u16* qW, const u16* kW, const u16* vW,
                                               const u16* qb, u16* MrT, u16* vWT, float* uv,
                                               const int* dflag){
  int fl = dflag[0];
  int i = blockIdx.x >> 7, f = blockIdx.x & 127, e = threadIdx.x;
  size_t qo = (size_t)(i * 128 + e) * 128;   // qW row e
  size_t ko = (size_t)(i * 128 + f) * 128;   // kW row f
  float m = 0.f;
  for (int d = 0; d < 128; ++d) m += ldf(qW, qo + d, fl) * ldf(kW, ko + d, fl);
  const float RS = 0.08838834764831845f;  // 1/sqrt(128)
  MrT[(i * 128 + f) * 128 + e] = f2b(m * RS);                 // MrowT[f][e] = M'[e,f]
  vWT[(i * 128 + f) * 128 + e] = f2b(ldf(vW, qo + f, fl));    // vWT[d][e] = vW[e][d]
  __shared__ float red[128];
  red[e] = ldf(kW, ko + e, fl) * ldf(qb, (size_t)i * 128 + e, fl);
  __syncthreads();
  for (int off = 64; off > 0; off >>= 1){
    if (e < off) red[e] += red[e + off];
    __syncthreads();
  }
  if (e == 0) uv[i * 128 + f] = red[0] * RS;
}

__global__ __launch_bounds__(256) void k_h1t(const u16* h1W, u16* h1WT, const int* dflag){
  int fl = dflag[0];
  __shared__ u16 tile[64][130];
  int k0 = blockIdx.x * 64, tid = threadIdx.x;
#pragma unroll 4
  for (int it = 0; it < 32; ++it){
    int r = it * 2 + (tid >> 7), c = tid & 127;
    tile[r][c] = f2b(ldf(h1W, (size_t)(k0 + r) * 128 + c, fl));
  }
  __syncthreads();
#pragma unroll 4
  for (int it = 0; it < 32; ++it){
    int idx = it * 256 + tid, n = idx >> 6, kk = idx & 63;
    h1WT[(size_t)n * 32896 + k0 + kk] = tile[kk][n];
  }
}

// -------- fused embed + 2 attention layers; h in LDS; one block = one batch --------

__global__ __launch_bounds__(512, 2) void k_fan(
    const u16* x, const u16* sW, const u16* sb, const u16* hW, const u16* hbe,
    const u16* MrT, const float* uv, const u16* vWT, const u16* vb,
    const u16* lng, const u16* lnb,
    u16* hgq, u16* se, int qoff, const int* dflag){
  __shared__ alignas(16) u16 hL[32768];    // h   [256 s][128 f], swz,  64KB
  __shared__ alignas(16) u16 vt[32768];    // vT  [128 d][256 t], swz2, 64KB
  __shared__ alignas(16) float c_all[256]; // c_t + LKOFF - 8, whole layer
  __shared__ float u_lds[128];             // u' for current layer
  int fl = dflag[0];
  int bl = blockIdx.x;
  int b = qoff + bl;
  int tid = threadIdx.x, w = tid >> 6, lane = tid & 63, l31 = lane & 31, q5 = lane >> 5;
  size_t xo = (size_t)b * 272;
  const float LKOFF = -20.72326584f;       // ln(1e-9); off-diag log-kernel value

  // scalar embedding (lanes 0..127)
  if (tid < 128){
    float acc = ldf(sb, tid, fl);
#pragma unroll
    for (int j = 0; j < 16; ++j) acc += ldf(x, xo + j, fl) * ldf(sW, (size_t)j * 128 + tid, fl);
    se[(size_t)b * 128 + tid] = f2b(acc);
  }
  // history embedding -> hL (pair-packed cvt_pk)
#pragma unroll
  for (int it = 0; it < 8; ++it){
    int c = it * 512 + tid, s = c >> 4, ch = c & 15;
    float xv = ldf(x, xo + 16 + s, fl);
    float f[8];
#pragma unroll
    for (int j = 0; j < 8; ++j)
      f[j] = xv * ldf(hW, ch * 8 + j, fl) + ldf(hbe, ch * 8 + j, fl);
    union { u32 u[4]; short8 v; } rr_;
#pragma unroll
    for (int j2 = 0; j2 < 4; ++j2) rr_.u[j2] = pk2(f[2 * j2], f[2 * j2 + 1]);
    *(short8*)((char*)hL + swz(s, ch)) = rr_.v;
  }

  int mtv = w & 3;                         // d-chunk for v producer
  int scol = 32 * w + l31;

#pragma unroll 1
  for (int li = 0; li < 2; ++li){
    const u16* Ta   = MrT + li * 16384;
    const u16* vWTi = vWT + li * 16384;
    if (tid < 128) u_lds[tid] = uv[li * 128 + tid];
    float vbl = ldf(vb, (size_t)li * 128 + 32 * mtv + l31, fl);
    __syncthreads();                 // hL (embed/prev epilogue) + u_lds visible

    // ---- qh_s = h_s.M' into registers: D[e][s] tiles, lane = col = s = scol.
    short8 qhf[8];
#pragma unroll
    for (int et = 0; et < 4; ++et){
      floatx16 qa = fz();
#pragma unroll 2
      for (int kc = 0; kc < 8; ++kc){
        short8 av = *(const short8*)(Ta + (32 * et + l31) * 128 + kc * 16 + q5 * 8);
        short8 bq = *(const short8*)((char*)hL + swz(32 * w + l31, 2 * kc + q5));
        qa = MF(av, bq, qa);
      }
      qhf[2 * et + 0] = frag_from(qa, 0, q5);   // e = 32et + 0..15
      qhf[2 * et + 1] = frag_from(qa, 1, q5);   // e = 32et + 16..31
    }

    // ---- c_all[t] = u'.h_t + (LKOFF - 8)  [softmax baseline folded in]
    {
      int row = 32 * w + l31;
      float dot = 0.f;
#pragma unroll 2
      for (int kc = 0; kc < 8; ++kc){
        int ch = 2 * kc + q5;
        short8 hv = *(const short8*)((char*)hL + swz(row, ch));
#pragma unroll
        for (int j = 0; j < 8; ++j) dot += u_lds[ch * 8 + j] * b2f(hv[j]);
      }
      dot += __shfl_xor(dot, 32);
      if (q5 == 0) c_all[row] = dot + (LKOFF - 8.f);
    }

    // ---- v producer: whole layer. vt[d][t] = sum_e h[t,e] vW[e,d] + vb[d].
    {
      const u16* Va = vWTi + (32 * mtv + l31) * 128 + q5 * 8;
#pragma unroll 1
      for (int u = 0; u < 4; ++u){
        int tc = (w >> 2) * 4 + u;
        floatx16 va = fz();
#pragma unroll 2
        for (int kc = 0; kc < 8; ++kc){
          short8 avV = *(const short8*)(Va + kc * 16);
          short8 bh  = *(const short8*)((char*)hL + swz(32 * tc + l31, 2 * kc + q5));
          va = MF(bh, avV, va);
        }
        // D[t][d]: lane = d-col, regs = t; 4 consecutive t -> one 8B chunk
#pragma unroll
        for (int qd = 0; qd < 4; ++qd){
          u32x2 pv;
          pv.x = pk2(va[4 * qd + 0] + vbl, va[4 * qd + 1] + vbl);
          pv.y = pk2(va[4 * qd + 2] + vbl, va[4 * qd + 3] + vbl);
          *(u32x2*)((char*)vt + swz2(32 * mtv + l31, 4 * tc + qd) + 8 * q5) = pv;
        }
      }
    }
    __syncthreads();               // vt + c_all complete

    float ls_a = 0.f, ls_b = 0.f;
    floatx16 oacc[4];
#pragma unroll
    for (int nt = 0; nt < 4; ++nt) oacc[nt] = fz();

    // ---- consumer: scores + exp + P@V over 8 t-subtiles; NO internal barriers
#pragma unroll 1
    for (int mt = 0; mt < 8; ++mt){
      floatx16 sa = fz();
      __builtin_amdgcn_s_setprio(1);
#pragma unroll
      for (int kc = 0; kc < 8; ++kc){
        short8 ah = *(const short8*)((char*)hL + swz(32 * mt + l31, 2 * kc + q5));
        sa = MF(ah, qhf[kc], sa);
      }
      __builtin_amdgcn_s_setprio(0);
      // softmax: v = sa + c2[tg]; diag removes the folded off-diag LKOFF.
#pragma unroll
      for (int g = 0; g < 4; ++g){
        f32x4 c4 = *(const f32x4*)&c_all[32 * mt + 8 * g + 4 * q5];
#pragma unroll
        for (int k = 0; k < 4; ++k){
          int reg = 4 * g + k;
          int tg = 32 * mt + 8 * g + 4 * q5 + k;
          float v = sa[reg] + c4[k];
          if (tg == scol) v -= LKOFF;
          v = fminf(fmaxf(v, -58.f), 42.f);
          float p = __expf(v);       // fixed-max softmax, shift folded into c2
          sa[reg] = p;
          if (reg & 1) ls_b += p; else ls_a += p;
        }
      }
      // pf frags computed BEFORE the bv loads so sa dies here (register diet)
      short8 pf0 = frag_from(sa, 0, q5);
      short8 pf1 = frag_from(sa, 1, q5);
      __builtin_amdgcn_s_setprio(1);
#pragma unroll
      for (int nt = 0; nt < 4; ++nt){
        short8 bv0 = *(const short8*)((char*)vt + swz2(32 * nt + l31, 4 * mt + 0 + q5));
        oacc[nt] = MF(pf0, bv0, oacc[nt]);
        short8 bv1 = *(const short8*)((char*)vt + swz2(32 * nt + l31, 4 * mt + 2 + q5));
        oacc[nt] = MF(pf1, bv1, oacc[nt]);
      }
      __builtin_amdgcn_s_setprio(0);
    }
    __syncthreads();                   // all hL reads done before epilogue writes

    // ---- epilogue: /l, +residual, LayerNorm, write back to hL (own rows only)
    // r23: group-of-4 batched butterfly — 8 independent shuffles per round,
    // only 8 extra live regs per group. Bit-identical per-reg sequence.
    float ls_tot = ls_a + ls_b;
    float l_run = ls_tot + __shfl_xor(ls_tot, 32);
    float linv = 1.f / l_run;
    float gv[4], bbv[4];
#pragma unroll
    for (int nt = 0; nt < 4; ++nt){
      gv[nt]  = ldf(lng, (size_t)li * 128 + 32 * nt + l31, fl);
      bbv[nt] = ldf(lnb, (size_t)li * 128 + 32 * nt + l31, fl);
    }
#pragma unroll 1
    for (int g4 = 0; g4 < 4; ++g4){
      float s1v[4], s2v[4];
      // pass 1: residual + scale, partials for the 4 regs of this group
#pragma unroll
      for (int j = 0; j < 4; ++j){
        int reg = 4 * g4 + j;
        int rr = (reg & 3) + 8 * (reg >> 2) + 4 * q5;
        int srow = 32 * w + rr;
        float lrv = __shfl(linv, rr);
        float s1 = 0.f, s2 = 0.f;
#pragma unroll
        for (int nt = 0; nt < 4; ++nt){
          int d = 32 * nt + l31;
          float res = b2f(*(const u16*)((char*)hL + swz(srow, d >> 3) + (d & 7) * 2));
          float v = oacc[nt][reg] * lrv + res;
          oacc[nt][reg] = v;
          s1 += v; s2 += v * v;
        }
        s1v[j] = s1; s2v[j] = s2;
      }
      // pass 2: batched butterfly, 8 independent shuffles per round
#pragma unroll
      for (int off = 1; off < 32; off <<= 1){
#pragma unroll
        for (int j = 0; j < 4; ++j){
          s1v[j] += __shfl_xor(s1v[j], off);
          s2v[j] += __shfl_xor(s2v[j], off);
        }
      }
      // pass 3: stats + normalize + write
#pragma unroll
      for (int j = 0; j < 4; ++j){
        int reg = 4 * g4 + j;
        int rr = (reg & 3) + 8 * (reg >> 2) + 4 * q5;
        int srow = 32 * w + rr;
        float mu = s1v[j] * 0.0078125f;
        float rs = rsqrtf(fmaxf(s2v[j] * 0.0078125f - mu * mu, 0.f) + 1e-5f);
#pragma unroll
        for (int nt = 0; nt < 4; ++nt){
          int d = 32 * nt + l31;
          float v = (oacc[nt][reg] - mu) * rs * gv[nt] + bbv[nt];
          *(u16*)((char*)hL + swz(srow, d >> 3) + (d & 7) * 2) = f2b(v);
        }
      }
    }
    __syncthreads();                   // hL update visible before next layer / store
  }

  // final h -> global, coalesced 16B chunks
#pragma unroll
  for (int it = 0; it < 8; ++it){
    int c = it * 512 + tid, row = c >> 4, ch = c & 15;
    *(short8*)(hgq + (size_t)bl * 32768 + row * 128 + ch * 8) =
        *(const short8*)((char*)hL + swz(row, ch));
  }
}

// ---------------- MLP head ----------------

__global__ __launch_bounds__(256) void k_mlp1(const u16* se, const u16* hgq, const u16* h1WT,
                                              float* part, int qoff, int nb){
  int mb = blockIdx.x, ks = blockIdx.y;
  int tid = threadIdx.x, w = tid >> 6, lane = tid & 63, l31 = lane & 31, q5 = lane >> 5;
  int b0 = mb * 32;
  floatx16 acc = fz();
  const u16* brow = h1WT + (size_t)(32 * w + l31) * 32896;
  int br = b0 + l31;
  const u16* seb = se + (size_t)(qoff + br) * 128;
  const u16* hb = hgq + (size_t)br * 32768;
  for (int kk = 0; kk < 257; ++kk){
    int kbase = ks * 4112 + kk * 16;
    const u16* ap = (kbase < 128) ? (seb + kbase + q5 * 8) : (hb + (kbase - 128) + q5 * 8);
    short8 a = *(const short8*)ap;
    short8 bf = *(const short8*)(brow + kbase + q5 * 8);
    acc = MF(a, bf, acc);
  }
#pragma unroll
  for (int reg = 0; reg < 16; ++reg){
    int rr = (reg & 3) + 8 * (reg >> 2) + 4 * q5;
    part[(size_t)ks * nb * 128 + (size_t)(b0 + rr) * 128 + 32 * w + l31] = acc[reg];
  }
}

__global__ __launch_bounds__(256) void k_mlp1red(const float* part, const u16* h1b, float* z1q,
                                                 const int* dflag, int nb){
  int fl = dflag[0];
  int idx = blockIdx.x * 256 + threadIdx.x;    // 0..nb*128-1
  float s = ldf(h1b, idx & 127, fl);
  size_t stride = (size_t)nb * 128;
#pragma unroll
  for (int ks = 0; ks < 8; ++ks) s += part[(size_t)ks * stride + idx];
  z1q[idx] = fmaxf(s, 0.f);
}

__global__ __launch_bounds__(256) void k_mlp2(const float* z1, const u16* h2W, const u16* h2b,
                                              float* z2, const int* dflag){
  int fl = dflag[0];
  int idx = blockIdx.x * 256 + threadIdx.x;    // 0..131071
  int b = idx >> 6, j = idx & 63;
  float s = ldf(h2b, j, fl);
  const float* zr = z1 + (size_t)b * 128;
  for (int k = 0; k < 128; ++k) s += zr[k] * ldf(h2W, (size_t)k * 64 + j, fl);
  z2[idx] = fmaxf(s, 0.f);
}

__global__ __launch_bounds__(256) void k_mlp3(const float* z2, const u16* h3W, const u16* h3b,
                                              void* out, const int* dflag){
  int fl = dflag[0];
  int b = blockIdx.x * 256 + threadIdx.x;      // 0..2047
  float s = ldf(h3b, 0, fl);
  const float* zr = z2 + (size_t)b * 64;
#pragma unroll
  for (int j = 0; j < 64; ++j) s += zr[j] * ldf(h3W, j, fl);
  if (!__builtin_isfinite(s)) s = 0.f;
  if (fl) ((float*)out)[b] = s;
  else    ((u16*)out)[b] = f2b(s);
}

// ---------------- launch ----------------

extern "C" void kernel_launch(void* const* d_in, const int* in_sizes, int n_in,
                              void* d_out, int out_size, void* d_ws, size_t ws_size,
                              hipStream_t stream) {
  const u16* x   = (const u16*)d_in[0];
  const u16* sW  = (const u16*)d_in[1];
  const u16* sb  = (const u16*)d_in[2];
  const u16* hW  = (const u16*)d_in[3];
  const u16* hb  = (const u16*)d_in[4];
  const u16* qW  = (const u16*)d_in[5];
  const u16* qb  = (const u16*)d_in[6];
  const u16* kW  = (const u16*)d_in[7];
  // d_in[8] = kb : cancels in softmax, unused
  const u16* vW  = (const u16*)d_in[9];
  const u16* vb  = (const u16*)d_in[10];
  const u16* lng = (const u16*)d_in[11];
  const u16* lnb = (const u16*)d_in[12];
  const u16* h1W = (const u16*)d_in[13];
  const u16* h1b = (const u16*)d_in[14];
  const u16* h2W = (const u16*)d_in[15];
  const u16* h2b = (const u16*)d_in[16];
  const u16* h3W = (const u16*)d_in[17];
  const u16* h3b = (const u16*)d_in[18];

  // full-pass mode (r5-r8 ran this branch); quarter mode fallback.
  const int nb = (ws_size >= 153600000ull) ? 2048 : 512;
  const int nq = 2048 / nb;

  char* W = (char*)d_ws;
  size_t o = 0;
  u16*   hg    = (u16*)(W + o); o += (size_t)nb * 65536;   // nb*32768*2
  u16*   h1WT  = (u16*)(W + o); o += 8421376;
  u16*   se    = (u16*)(W + o); o += 524288;               // always full 2048x128 bf16
  u16*   MrT   = (u16*)(W + o); o += 65536;
  u16*   vWT   = (u16*)(W + o); o += 65536;
  float* uv    = (float*)(W + o); o += 1024;
  float* part  = (float*)(W + o); o += (size_t)nb * 4096;  // 8 * nb*128 * 4B
  float* z1    = (float*)(W + o); o += 1048576;            // always full
  float* z2    = (float*)(W + o); o += 524288;
  int*   dflag = (int*)(W + o);

  k_detect<<<1, 256, 0, stream>>>(x, dflag);
  k_prepw<<<256, 128, 0, stream>>>(qW, kW, vW, qb, MrT, vWT, uv, dflag);
  k_h1t<<<514, 256, 0, stream>>>(h1W, h1WT, dflag);

  for (int q = 0; q < nq; ++q){
    int qoff = q * nb;
    k_fan<<<nb, 512, 0, stream>>>(x, sW, sb, hW, hb, MrT, uv, vWT, vb,
                                  lng, lnb, hg, se, qoff, dflag);
    k_mlp1<<<dim3(nb / 32, 8), 256, 0, stream>>>(se, hg, h1WT, part, qoff, nb);
    k_mlp1red<<<nb / 2, 256, 0, stream>>>(part, h1b, z1 + (size_t)qoff * 128, dflag, nb);
  }

  k_mlp2<<<512, 256, 0, stream>>>(z1, h2W, h2b, z2, dflag);
  k_mlp3<<<8, 256, 0, stream>>>(z2, h3W, h3b, d_out, dflag);
}

// Round 14
// 945.819 us; speedup vs baseline: 1.1439x; 1.0537x over previous
//
#include <hip/hip_runtime.h>
#include <hip/hip_bf16.h>
#include <cstddef>

// FAN_39273180955145 — round 24. r23 (791us k_fan, VGPR 104, ZERO spill)
// confirmed: register-bounded latency cuts land ~1:1 in wall time; kernel is
// dependence-chain-bound at 2 waves/SIMD (VALU 33 / MFMA 11 / HBM 2%).
// r24 pairs the remaining serial chains, using the freed register headroom:
//  * consumer mt-PAIRING: sa0/sa1 independent MFMA chains interleaved
//    (halves the 8-deep dependent-MFMA latency), softmax x2, 4 pf frags,
//    16 PV MFMAs over 4 independent oacc chains. +32 accum live — fits now.
//  * v-producer u-PAIRING: va0/va1 dual chains sharing avV global loads
//    (halves vWT reads); oacc not live in that phase.
//  * ls split into 4 accumulators (chain decouple; positive-sum reorder only).
// Everything else byte-identical to r23 (kh-free qh-in-regs, cvt_pk packing,
// softmax folding, group-of-4 LN butterfly, 3 barriers/layer, (512,2)).

typedef unsigned short u16;
typedef unsigned int u32;
typedef short short8 __attribute__((ext_vector_type(8)));
typedef u32 u32x2 __attribute__((ext_vector_type(2)));
typedef float floatx16 __attribute__((ext_vector_type(16)));
typedef float f32x4 __attribute__((ext_vector_type(4)));

__device__ __forceinline__ float b2f(u16 u){ return __uint_as_float(((u32)u) << 16); }
__device__ __forceinline__ u16 f2b(float f){
  __hip_bfloat16 h = __float2bfloat16(f);          // RNE, = old manual round
  return *reinterpret_cast<u16*>(&h);
}
__device__ __forceinline__ u32 pk2(float a, float b){
  float2 t; t.x = a; t.y = b;
  __hip_bfloat162 h = __float22bfloat162_rn(t);    // v_cvt_pk_bf16_f32 (lo=a)
  return *reinterpret_cast<u32*>(&h);
}
// flagged input load: f32 ? fp32 : bf16; non-finite -> 0
__device__ __forceinline__ float ldf(const u16* p, size_t i, int f32){
  float v = f32 ? ((const float*)p)[i] : b2f(p[i]);
  return __builtin_isfinite(v) ? v : 0.f;
}
// [rows][128 bf16] region, 256B rows, 16B-chunk xor swizzle
__device__ __forceinline__ int swz(int row, int ch){ return (row << 8) | ((ch ^ (row & 15)) << 4); }
// [rows][256 bf16] region, 512B rows, 32 chunks; xor low4 only (bijective)
__device__ __forceinline__ int swz2(int row, int ch){ return (row << 9) | ((ch ^ (row & 15)) << 4); }
__device__ __forceinline__ floatx16 fz(){
  floatx16 z;
#pragma unroll
  for (int i = 0; i < 16; ++i) z[i] = 0.f;
  return z;
}
__device__ __forceinline__ floatx16 MF(short8 a, short8 b, floatx16 c){
  return __builtin_amdgcn_mfma_f32_32x32x16_bf16(a, b, c, 0, 0, 0);
}
// C-layout 32x32 tile (by value) -> k-chunk fragment via xor-32 exchange
// (r4-verified). cvt_pk packing + verified __shfl_xor lane exchange.
__device__ __forceinline__ short8 frag_from(floatx16 cv, int half, int q5){
  int r0 = half * 8;
  u32 e01 = pk2(cv[r0 + 0], cv[r0 + 1]);
  u32 e23 = pk2(cv[r0 + 2], cv[r0 + 3]);
  u32 o01 = pk2(cv[r0 + 4], cv[r0 + 5]);
  u32 o23 = pk2(cv[r0 + 6], cv[r0 + 7]);
  u32 s0 = q5 ? e01 : o01;
  u32 s1 = q5 ? e23 : o23;
  u32 r0v = __shfl_xor(s0, 32);
  u32 r1v = __shfl_xor(s1, 32);
  union { u32 u[4]; short8 v; } un;
  un.u[0] = q5 ? r0v : e01;
  un.u[1] = q5 ? r1v : e23;
  un.u[2] = q5 ? o01 : r0v;
  un.u[3] = q5 ? o23 : r1v;
  return un.v;
}

// ---------------- dtype detector (r4-verified) ----------------
__global__ __launch_bounds__(256) void k_detect(const u16* x, int* dflag){
  __shared__ int red[256];
  int t = threadIdx.x, cnt = 0;
  for (int i = t; i < 4096; i += 256){
    u16 v = x[2 * i];
    int e = (v >> 7) & 0xFF;
    if (e == 0xFF || e >= 0x90 || (e > 0 && e <= 0x20)) ++cnt;
  }
  red[t] = cnt;
  __syncthreads();
  for (int off = 128; off > 0; off >>= 1){
    if (t < off) red[t] += red[t + off];
    __syncthreads();
  }
  if (t == 0) dflag[0] = (red[0] > 1000) ? 1 : 0;
}

// ---------------- prep kernels ----------------

// MrowT[a][b] = M'[b,a]; vWT[d][e] = vW[e][d]; uv = u'.
__global__ __launch_bounds__(128) void k_prepw(const u16* qW, const u16* kW, const u16* vW,
                                               const u16* qb, u16* MrT, u16* vWT, float* uv,
                                               const int* dflag){
  int fl = dflag[0];
  int i = blockIdx.x >> 7, f = blockIdx.x & 127, e = threadIdx.x;
  size_t qo = (size_t)(i * 128 + e) * 128;   // qW row e
  size_t ko = (size_t)(i * 128 + f) * 128;   // kW row f
  float m = 0.f;
  for (int d = 0; d < 128; ++d) m += ldf(qW, qo + d, fl) * ldf(kW, ko + d, fl);
  const float RS = 0.08838834764831845f;  // 1/sqrt(128)
  MrT[(i * 128 + f) * 128 + e] = f2b(m * RS);                 // MrowT[f][e] = M'[e,f]
  vWT[(i * 128 + f) * 128 + e] = f2b(ldf(vW, qo + f, fl));    // vWT[d][e] = vW[e][d]
  __shared__ float red[128];
  red[e] = ldf(kW, ko + e, fl) * ldf(qb, (size_t)i * 128 + e, fl);
  __syncthreads();
  for (int off = 64; off > 0; off >>= 1){
    if (e < off) red[e] += red[e + off];
    __syncthreads();
  }
  if (e == 0) uv[i * 128 + f] = red[0] * RS;
}

__global__ __launch_bounds__(256) void k_h1t(const u16* h1W, u16* h1WT, const int* dflag){
  int fl = dflag[0];
  __shared__ u16 tile[64][130];
  int k0 = blockIdx.x * 64, tid = threadIdx.x;
#pragma unroll 4
  for (int it = 0; it < 32; ++it){
    int r = it * 2 + (tid >> 7), c = tid & 127;
    tile[r][c] = f2b(ldf(h1W, (size_t)(k0 + r) * 128 + c, fl));
  }
  __syncthreads();
#pragma unroll 4
  for (int it = 0; it < 32; ++it){
    int idx = it * 256 + tid, n = idx >> 6, kk = idx & 63;
    h1WT[(size_t)n * 32896 + k0 + kk] = tile[kk][n];
  }
}

// -------- fused embed + 2 attention layers; h in LDS; one block = one batch --------

__global__ __launch_bounds__(512, 2) void k_fan(
    const u16* x, const u16* sW, const u16* sb, const u16* hW, const u16* hbe,
    const u16* MrT, const float* uv, const u16* vWT, const u16* vb,
    const u16* lng, const u16* lnb,
    u16* hgq, u16* se, int qoff, const int* dflag){
  __shared__ alignas(16) u16 hL[32768];    // h   [256 s][128 f], swz,  64KB
  __shared__ alignas(16) u16 vt[32768];    // vT  [128 d][256 t], swz2, 64KB
  __shared__ alignas(16) float c_all[256]; // c_t + LKOFF - 8, whole layer
  __shared__ float u_lds[128];             // u' for current layer
  int fl = dflag[0];
  int bl = blockIdx.x;
  int b = qoff + bl;
  int tid = threadIdx.x, w = tid >> 6, lane = tid & 63, l31 = lane & 31, q5 = lane >> 5;
  size_t xo = (size_t)b * 272;
  const float LKOFF = -20.72326584f;       // ln(1e-9); off-diag log-kernel value

  // scalar embedding (lanes 0..127)
  if (tid < 128){
    float acc = ldf(sb, tid, fl);
#pragma unroll
    for (int j = 0; j < 16; ++j) acc += ldf(x, xo + j, fl) * ldf(sW, (size_t)j * 128 + tid, fl);
    se[(size_t)b * 128 + tid] = f2b(acc);
  }
  // history embedding -> hL (pair-packed cvt_pk)
#pragma unroll
  for (int it = 0; it < 8; ++it){
    int c = it * 512 + tid, s = c >> 4, ch = c & 15;
    float xv = ldf(x, xo + 16 + s, fl);
    float f[8];
#pragma unroll
    for (int j = 0; j < 8; ++j)
      f[j] = xv * ldf(hW, ch * 8 + j, fl) + ldf(hbe, ch * 8 + j, fl);
    union { u32 u[4]; short8 v; } rr_;
#pragma unroll
    for (int j2 = 0; j2 < 4; ++j2) rr_.u[j2] = pk2(f[2 * j2], f[2 * j2 + 1]);
    *(short8*)((char*)hL + swz(s, ch)) = rr_.v;
  }

  int mtv = w & 3;                         // d-chunk for v producer
  int scol = 32 * w + l31;

#pragma unroll 1
  for (int li = 0; li < 2; ++li){
    const u16* Ta   = MrT + li * 16384;
    const u16* vWTi = vWT + li * 16384;
    if (tid < 128) u_lds[tid] = uv[li * 128 + tid];
    float vbl = ldf(vb, (size_t)li * 128 + 32 * mtv + l31, fl);
    __syncthreads();                 // hL (embed/prev epilogue) + u_lds visible

    // ---- qh_s = h_s.M' into registers: D[e][s] tiles, lane = col = s = scol.
    short8 qhf[8];
#pragma unroll
    for (int et = 0; et < 4; ++et){
      floatx16 qa = fz();
#pragma unroll 2
      for (int kc = 0; kc < 8; ++kc){
        short8 av = *(const short8*)(Ta + (32 * et + l31) * 128 + kc * 16 + q5 * 8);
        short8 bq = *(const short8*)((char*)hL + swz(32 * w + l31, 2 * kc + q5));
        qa = MF(av, bq, qa);
      }
      qhf[2 * et + 0] = frag_from(qa, 0, q5);   // e = 32et + 0..15
      qhf[2 * et + 1] = frag_from(qa, 1, q5);   // e = 32et + 16..31
    }

    // ---- c_all[t] = u'.h_t + (LKOFF - 8)  [softmax baseline folded in]
    {
      int row = 32 * w + l31;
      float dot = 0.f;
#pragma unroll 2
      for (int kc = 0; kc < 8; ++kc){
        int ch = 2 * kc + q5;
        short8 hv = *(const short8*)((char*)hL + swz(row, ch));
#pragma unroll
        for (int j = 0; j < 8; ++j) dot += u_lds[ch * 8 + j] * b2f(hv[j]);
      }
      dot += __shfl_xor(dot, 32);
      if (q5 == 0) c_all[row] = dot + (LKOFF - 8.f);
    }

    // ---- v producer: whole layer, u-PAIRED dual chains sharing avV loads.
    // vt[d][t] = sum_e h[t,e] vW[e,d] + vb[d].
    {
      const u16* Va = vWTi + (32 * mtv + l31) * 128 + q5 * 8;
#pragma unroll 1
      for (int up = 0; up < 2; ++up){
        int tc0 = (w >> 2) * 4 + 2 * up, tc1 = tc0 + 1;
        floatx16 va0 = fz(), va1 = fz();
#pragma unroll 2
        for (int kc = 0; kc < 8; ++kc){
          short8 avV = *(const short8*)(Va + kc * 16);
          short8 bh0 = *(const short8*)((char*)hL + swz(32 * tc0 + l31, 2 * kc + q5));
          short8 bh1 = *(const short8*)((char*)hL + swz(32 * tc1 + l31, 2 * kc + q5));
          va0 = MF(bh0, avV, va0);
          va1 = MF(bh1, avV, va1);
        }
        // D[t][d]: lane = d-col, regs = t; 4 consecutive t -> one 8B chunk
#pragma unroll
        for (int qd = 0; qd < 4; ++qd){
          u32x2 pv;
          pv.x = pk2(va0[4 * qd + 0] + vbl, va0[4 * qd + 1] + vbl);
          pv.y = pk2(va0[4 * qd + 2] + vbl, va0[4 * qd + 3] + vbl);
          *(u32x2*)((char*)vt + swz2(32 * mtv + l31, 4 * tc0 + qd) + 8 * q5) = pv;
        }
#pragma unroll
        for (int qd = 0; qd < 4; ++qd){
          u32x2 pv;
          pv.x = pk2(va1[4 * qd + 0] + vbl, va1[4 * qd + 1] + vbl);
          pv.y = pk2(va1[4 * qd + 2] + vbl, va1[4 * qd + 3] + vbl);
          *(u32x2*)((char*)vt + swz2(32 * mtv + l31, 4 * tc1 + qd) + 8 * q5) = pv;
        }
      }
    }
    __syncthreads();               // vt + c_all complete

    float ls00 = 0.f, ls01 = 0.f, ls10 = 0.f, ls11 = 0.f;
    floatx16 oacc[4];
#pragma unroll
    for (int nt = 0; nt < 4; ++nt) oacc[nt] = fz();

    // ---- consumer: mt-PAIRED scores + exp + P@V; NO internal barriers
#pragma unroll 1
    for (int mtp = 0; mtp < 4; ++mtp){
      int mt0 = 2 * mtp, mt1 = 2 * mtp + 1;
      floatx16 sa0 = fz(), sa1 = fz();
      __builtin_amdgcn_s_setprio(1);
#pragma unroll
      for (int kc = 0; kc < 8; ++kc){
        short8 ah0 = *(const short8*)((char*)hL + swz(32 * mt0 + l31, 2 * kc + q5));
        short8 ah1 = *(const short8*)((char*)hL + swz(32 * mt1 + l31, 2 * kc + q5));
        sa0 = MF(ah0, qhf[kc], sa0);
        sa1 = MF(ah1, qhf[kc], sa1);
      }
      __builtin_amdgcn_s_setprio(0);
      // softmax on sa0 (v = sa + c2[tg]; diag removes folded off-diag LKOFF)
#pragma unroll
      for (int g = 0; g < 4; ++g){
        f32x4 c4 = *(const f32x4*)&c_all[32 * mt0 + 8 * g + 4 * q5];
#pragma unroll
        for (int k = 0; k < 4; ++k){
          int reg = 4 * g + k;
          int tg = 32 * mt0 + 8 * g + 4 * q5 + k;
          float v = sa0[reg] + c4[k];
          if (tg == scol) v -= LKOFF;
          v = fminf(fmaxf(v, -58.f), 42.f);
          float p = __expf(v);
          sa0[reg] = p;
          if (reg & 1) ls01 += p; else ls00 += p;
        }
      }
      // softmax on sa1
#pragma unroll
      for (int g = 0; g < 4; ++g){
        f32x4 c4 = *(const f32x4*)&c_all[32 * mt1 + 8 * g + 4 * q5];
#pragma unroll
        for (int k = 0; k < 4; ++k){
          int reg = 4 * g + k;
          int tg = 32 * mt1 + 8 * g + 4 * q5 + k;
          float v = sa1[reg] + c4[k];
          if (tg == scol) v -= LKOFF;
          v = fminf(fmaxf(v, -58.f), 42.f);
          float p = __expf(v);
          sa1[reg] = p;
          if (reg & 1) ls11 += p; else ls10 += p;
        }
      }
      // pf frags BEFORE the bv loads so sa0/sa1 die here
      short8 pf00 = frag_from(sa0, 0, q5);
      short8 pf01 = frag_from(sa0, 1, q5);
      short8 pf10 = frag_from(sa1, 0, q5);
      short8 pf11 = frag_from(sa1, 1, q5);
      __builtin_amdgcn_s_setprio(1);
#pragma unroll
      for (int nt = 0; nt < 4; ++nt){
        short8 bv;
        bv = *(const short8*)((char*)vt + swz2(32 * nt + l31, 4 * mt0 + 0 + q5));
        oacc[nt] = MF(pf00, bv, oacc[nt]);
        bv = *(const short8*)((char*)vt + swz2(32 * nt + l31, 4 * mt0 + 2 + q5));
        oacc[nt] = MF(pf01, bv, oacc[nt]);
        bv = *(const short8*)((char*)vt + swz2(32 * nt + l31, 4 * mt1 + 0 + q5));
        oacc[nt] = MF(pf10, bv, oacc[nt]);
        bv = *(const short8*)((char*)vt + swz2(32 * nt + l31, 4 * mt1 + 2 + q5));
        oacc[nt] = MF(pf11, bv, oacc[nt]);
      }
      __builtin_amdgcn_s_setprio(0);
    }
    __syncthreads();                   // all hL reads done before epilogue writes

    // ---- epilogue: /l, +residual, LayerNorm, write back to hL (own rows only)
    // group-of-4 batched butterfly (r23): 8 independent shuffles per round.
    float ls_tot = (ls00 + ls01) + (ls10 + ls11);
    float l_run = ls_tot + __shfl_xor(ls_tot, 32);
    float linv = 1.f / l_run;
    float gv[4], bbv[4];
#pragma unroll
    for (int nt = 0; nt < 4; ++nt){
      gv[nt]  = ldf(lng, (size_t)li * 128 + 32 * nt + l31, fl);
      bbv[nt] = ldf(lnb, (size_t)li * 128 + 32 * nt + l31, fl);
    }
#pragma unroll 1
    for (int g4 = 0; g4 < 4; ++g4){
      float s1v[4], s2v[4];
      // pass 1: residual + scale, partials for the 4 regs of this group
#pragma unroll
      for (int j = 0; j < 4; ++j){
        int reg = 4 * g4 + j;
        int rr = (reg & 3) + 8 * (reg >> 2) + 4 * q5;
        int srow = 32 * w + rr;
        float lrv = __shfl(linv, rr);
        float s1 = 0.f, s2 = 0.f;
#pragma unroll
        for (int nt = 0; nt < 4; ++nt){
          int d = 32 * nt + l31;
          float res = b2f(*(const u16*)((char*)hL + swz(srow, d >> 3) + (d & 7) * 2));
          float v = oacc[nt][reg] * lrv + res;
          oacc[nt][reg] = v;
          s1 += v; s2 += v * v;
        }
        s1v[j] = s1; s2v[j] = s2;
      }
      // pass 2: batched butterfly, 8 independent shuffles per round
#pragma unroll
      for (int off = 1; off < 32; off <<= 1){
#pragma unroll
        for (int j = 0; j < 4; ++j){
          s1v[j] += __shfl_xor(s1v[j], off);
          s2v[j] += __shfl_xor(s2v[j], off);
        }
      }
      // pass 3: stats + normalize + write
#pragma unroll
      for (int j = 0; j < 4; ++j){
        int reg = 4 * g4 + j;
        int rr = (reg & 3) + 8 * (reg >> 2) + 4 * q5;
        int srow = 32 * w + rr;
        float mu = s1v[j] * 0.0078125f;
        float rs = rsqrtf(fmaxf(s2v[j] * 0.0078125f - mu * mu, 0.f) + 1e-5f);
#pragma unroll
        for (int nt = 0; nt < 4; ++nt){
          int d = 32 * nt + l31;
          float v = (oacc[nt][reg] - mu) * rs * gv[nt] + bbv[nt];
          *(u16*)((char*)hL + swz(srow, d >> 3) + (d & 7) * 2) = f2b(v);
        }
      }
    }
    __syncthreads();                   // hL update visible before next layer / store
  }

  // final h -> global, coalesced 16B chunks
#pragma unroll
  for (int it = 0; it < 8; ++it){
    int c = it * 512 + tid, row = c >> 4, ch = c & 15;
    *(short8*)(hgq + (size_t)bl * 32768 + row * 128 + ch * 8) =
        *(const short8*)((char*)hL + swz(row, ch));
  }
}

// ---------------- MLP head ----------------

__global__ __launch_bounds__(256) void k_mlp1(const u16* se, const u16* hgq, const u16* h1WT,
                                              float* part, int qoff, int nb){
  int mb = blockIdx.x, ks = blockIdx.y;
  int tid = threadIdx.x, w = tid >> 6, lane = tid & 63, l31 = lane & 31, q5 = lane >> 5;
  int b0 = mb * 32;
  floatx16 acc = fz();
  const u16* brow = h1WT + (size_t)(32 * w + l31) * 32896;
  int br = b0 + l31;
  const u16* seb = se + (size_t)(qoff + br) * 128;
  const u16* hb = hgq + (size_t)br * 32768;
  for (int kk = 0; kk < 257; ++kk){
    int kbase = ks * 4112 + kk * 16;
    const u16* ap = (kbase < 128) ? (seb + kbase + q5 * 8) : (hb + (kbase - 128) + q5 * 8);
    short8 a = *(const short8*)ap;
    short8 bf = *(const short8*)(brow + kbase + q5 * 8);
    acc = MF(a, bf, acc);
  }
#pragma unroll
  for (int reg = 0; reg < 16; ++reg){
    int rr = (reg & 3) + 8 * (reg >> 2) + 4 * q5;
    part[(size_t)ks * nb * 128 + (size_t)(b0 + rr) * 128 + 32 * w + l31] = acc[reg];
  }
}

__global__ __launch_bounds__(256) void k_mlp1red(const float* part, const u16* h1b, float* z1q,
                                                 const int* dflag, int nb){
  int fl = dflag[0];
  int idx = blockIdx.x * 256 + threadIdx.x;    // 0..nb*128-1
  float s = ldf(h1b, idx & 127, fl);
  size_t stride = (size_t)nb * 128;
#pragma unroll
  for (int ks = 0; ks < 8; ++ks) s += part[(size_t)ks * stride + idx];
  z1q[idx] = fmaxf(s, 0.f);
}

__global__ __launch_bounds__(256) void k_mlp2(const float* z1, const u16* h2W, const u16* h2b,
                                              float* z2, const int* dflag){
  int fl = dflag[0];
  int idx = blockIdx.x * 256 + threadIdx.x;    // 0..131071
  int b = idx >> 6, j = idx & 63;
  float s = ldf(h2b, j, fl);
  const float* zr = z1 + (size_t)b * 128;
  for (int k = 0; k < 128; ++k) s += zr[k] * ldf(h2W, (size_t)k * 64 + j, fl);
  z2[idx] = fmaxf(s, 0.f);
}

__global__ __launch_bounds__(256) void k_mlp3(const float* z2, const u16* h3W, const u16* h3b,
                                              void* out, const int* dflag){
  int fl = dflag[0];
  int b = blockIdx.x * 256 + threadIdx.x;      // 0..2047
  float s = ldf(h3b, 0, fl);
  const float* zr = z2 + (size_t)b * 64;
#pragma unroll
  for (int j = 0; j < 64; ++j) s += zr[j] * ldf(h3W, j, fl);
  if (!__builtin_isfinite(s)) s = 0.f;
  if (fl) ((float*)out)[b] = s;
  else    ((u16*)out)[b] = f2b(s);
}

// ---------------- launch ----------------

extern "C" void kernel_launch(void* const* d_in, const int* in_sizes, int n_in,
                              void* d_out, int out_size, void* d_ws, size_t ws_size,
                              hipStream_t stream) {
  const u16* x   = (const u16*)d_in[0];
  const u16* sW  = (const u16*)d_in[1];
  const u16* sb  = (const u16*)d_in[2];
  const u16* hW  = (const u16*)d_in[3];
  const u16* hb  = (const u16*)d_in[4];
  const u16* qW  = (const u16*)d_in[5];
  const u16* qb  = (const u16*)d_in[6];
  const u16* kW  = (const u16*)d_in[7];
  // d_in[8] = kb : cancels in softmax, unused
  const u16* vW  = (const u16*)d_in[9];
  const u16* vb  = (const u16*)d_in[10];
  const u16* lng = (const u16*)d_in[11];
  const u16* lnb = (const u16*)d_in[12];
  const u16* h1W = (const u16*)d_in[13];
  const u16* h1b = (const u16*)d_in[14];
  const u16* h2W = (const u16*)d_in[15];
  const u16* h2b = (const u16*)d_in[16];
  const u16* h3W = (const u16*)d_in[17];
  const u16* h3b = (const u16*)d_in[18];

  // full-pass mode (r5-r8 ran this branch); quarter mode fallback.
  const int nb = (ws_size >= 153600000ull) ? 2048 : 512;
  const int nq = 2048 / nb;

  char* W = (char*)d_ws;
  size_t o = 0;
  u16*   hg    = (u16*)(W + o); o += (size_t)nb * 65536;   // nb*32768*2
  u16*   h1WT  = (u16*)(W + o); o += 8421376;
  u16*   se    = (u16*)(W + o); o += 524288;               // always full 2048x128 bf16
  u16*   MrT   = (u16*)(W + o); o += 65536;
  u16*   vWT   = (u16*)(W + o); o += 65536;
  float* uv    = (float*)(W + o); o += 1024;
  float* part  = (float*)(W + o); o += (size_t)nb * 4096;  // 8 * nb*128 * 4B
  float* z1    = (float*)(W + o); o += 1048576;            // always full
  float* z2    = (float*)(W + o); o += 524288;
  int*   dflag = (int*)(W + o);

  k_detect<<<1, 256, 0, stream>>>(x, dflag);
  k_prepw<<<256, 128, 0, stream>>>(qW, kW, vW, qb, MrT, vWT, uv, dflag);
  k_h1t<<<514, 256, 0, stream>>>(h1W, h1WT, dflag);

  for (int q = 0; q < nq; ++q){
    int qoff = q * nb;
    k_fan<<<nb, 512, 0, stream>>>(x, sW, sb, hW, hb, MrT, uv, vWT, vb,
                                  lng, lnb, hg, se, qoff, dflag);
    k_mlp1<<<dim3(nb / 32, 8), 256, 0, stream>>>(se, hg, h1WT, part, qoff, nb);
    k_mlp1red<<<nb / 2, 256, 0, stream>>>(part, h1b, z1 + (size_t)qoff * 128, dflag, nb);
  }

  k_mlp2<<<512, 256, 0, stream>>>(z1, h2W, h2b, z2, dflag);
  k_mlp3<<<8, 256, 0, stream>>>(z2, h3W, h3b, d_out, dflag);
}